// Round 9
// baseline (357.652 us; speedup 1.0000x reference)
//
#include <hip/hip_runtime.h>
#include <stdint.h>
#include <stddef.h>

#define LN_EPS 1e-5f

typedef __bf16 bf16;
typedef __bf16 bf16x8 __attribute__((ext_vector_type(8)));
typedef __bf16 bf16x4 __attribute__((ext_vector_type(4)));
typedef float f32x4 __attribute__((ext_vector_type(4)));

// async global->LDS, 16B per lane. LDS dest must be wave-uniform base + lane*16.
#define GL16(gp, lp)                                                                   \
  __builtin_amdgcn_global_load_lds((__attribute__((address_space(1))) uint32_t*)(gp),  \
                                   (__attribute__((address_space(3))) uint32_t*)(lp),  \
                                   16, 0, 0)

#define SBAR   asm volatile("s_barrier" ::: "memory")
#define VMW(N) asm volatile("s_waitcnt vmcnt(" #N ")" ::: "memory")
#define LGK(N) asm volatile("s_waitcnt lgkmcnt(" #N ")" ::: "memory")
#define SCB    __builtin_amdgcn_sched_barrier(0)
#define SP1    __builtin_amdgcn_s_setprio(1)
#define SP0    __builtin_amdgcn_s_setprio(0)
#define NOWAIT ((void)0)

// ---------------------------------------------------------------------------
// fp32 -> bf16 convert, grid-strided: 1680 blocks x 256 thr x 16 iters exact.
// ---------------------------------------------------------------------------
#define XV4   6291456           // x:      25,165,824 f32 / 4
#define WQV4  442368            // w_qkv:   1,769,472 f32 / 4
#define WPV4  147456            // w_proj:    589,824 f32 / 4  (total v4 = 6,881,280)
__global__ __launch_bounds__(256) void cvt_all(const float* __restrict__ x,
                                               const float* __restrict__ wq,
                                               const float* __restrict__ wp,
                                               bf16* __restrict__ xb,
                                               bf16* __restrict__ wqb,
                                               bf16* __restrict__ wpb) {
  const int base = blockIdx.x * 256 + threadIdx.x;   // stride 430,080
#pragma unroll 1
  for (int it = 0; it < 16; ++it) {
    const int i = base + it * 430080;
    const float* src; bf16* dst; int off;
    if (i < XV4)              { src = x;  dst = xb;  off = i; }
    else if (i < XV4 + WQV4)  { src = wq; dst = wqb; off = i - XV4; }
    else                      { src = wp; dst = wpb; off = i - (XV4 + WQV4); }
    const float4 v = ((const float4*)src)[off];
    bf16x4 o;
    o[0] = (bf16)v.x; o[1] = (bf16)v.y; o[2] = (bf16)v.z; o[3] = (bf16)v.w;
    ((bf16x4*)dst)[off] = o;
  }
}

// ---------------------------------------------------------------------------
// Core C (r9): 128x256 tile, BK=32, double-buffered, 2 blocks/CU.
// 8 waves (2M x 4N), per-wave 64x64 = 4x4 frags, 16 MFMA per K-tile.
// LDS/buf: A[128][32] (8KB) + B[256][32] (16KB) = 24KB; 2 bufs = 48KB.
// Staging: 3 GL16/thread/K-tile (A row tid>>2; B rows tid>>2, 128+tid>>2).
// Swizzle: LDS chunk-pos p holds global chunk p ^ ((row>>1)&3); applied on
// GL16 SOURCE col (dest linear) and ds_read chunk -> 2-way (free) reads.
// Per K-tile t (cur = t&1):
//   8 ds_read(buf[cur]); lgkmcnt(0); s_barrier   <- all waves' reads retired
//   stage(t+2 -> buf[cur])                        <- safe overwrite
//   16 MFMA (reg-only); vmcnt(3)                  <- completes tile t+1
//   s_barrier                                     <- publish t+1
// vmcnt ledger (3 GL16/stage): prologue {t0,t1}=6, VMW(3)->t0; steady:
// {t+1}=3 +stage(t+2)=6, VMW(3)->t+1; t=22: no stage, VMW(0)->t23; t=23 none.
// 2 barriers/K-tile (48 total, half of r8) + 2 blocks/CU -> one block's
// barrier stalls overlap the other block's compute (m114 mechanism).
// ---------------------------------------------------------------------------
#define CSTAGE(T, CUR) do {                                    \
    GL16(cA  + (T) * 32, sh + (CUR) * 12288 + tid8);           \
    GL16(cB0 + (T) * 32, sh + (CUR) * 12288 + 4096 + tid8);    \
    GL16(cB1 + (T) * 32, sh + (CUR) * 12288 + 8192 + tid8);    \
  } while (0)

#define CRD(CUR) do {                                                         \
    _Pragma("unroll") for (int ff = 0; ff < 4; ++ff) {                        \
      const int ra = wm * 64 + ff * 16 + l16;                                 \
      const int rb = wn * 64 + ff * 16 + l16;                                 \
      aF[ff] = *(const bf16x8*)(sh + (CUR) * 12288 + ra * 32 + coff);         \
      bF[ff] = *(const bf16x8*)(sh + (CUR) * 12288 + 4096 + rb * 32 + coff);  \
    } } while (0)

#define CMM do {                                                              \
    _Pragma("unroll") for (int ai = 0; ai < 4; ++ai)                          \
      _Pragma("unroll") for (int bj = 0; bj < 4; ++bj)                        \
        acc[ai][bj] = __builtin_amdgcn_mfma_f32_16x16x32_bf16(                \
            aF[ai], bF[bj], acc[ai][bj], 0, 0, 0);                            \
  } while (0)

#define CITER(CUR, STG, WAIT) do {  \
    CRD(CUR);                       \
    LGK(0); SCB;                    \
    SBAR;                           \
    STG;                            \
    SP1; CMM; SP0;                  \
    WAIT;                           \
    SBAR;                           \
  } while (0)

__device__ __forceinline__ void gemmC(const bf16* cA, const bf16* cB0,
                                      const bf16* cB1, bf16* sh,
                                      f32x4 acc[4][4]) {
  const int tid  = threadIdx.x;
  const int lane = tid & 63;
  const int wave = tid >> 6;
  const int wm   = wave >> 2;          // M-half (64 rows)
  const int wn   = wave & 3;           // N-quadrant (64 cols)
  const int l16  = lane & 15;
  const int qg   = lane >> 4;
  const int tid8 = tid * 8;
  // read chunk offset: qg ^ ((row>>1)&3) with row = *64*wm/wn + 16*ff + l16
  // -> (row>>1)&3 == (l16>>1)&3 (other terms are multiples of 4): lane-const.
  const int coff = ((qg ^ ((l16 >> 1) & 3)) << 3);
  bf16x8 aF[4], bF[4];

  CSTAGE(0, 0); CSTAGE(1, 1);
  VMW(3);                              // tile 0 resident
  SBAR;

#pragma unroll 1
  for (int t = 0; t < 22; t += 2) {
    CITER(0, CSTAGE(t + 2, 0), VMW(3));
    CITER(1, CSTAGE(t + 3, 1), VMW(3));
  }
  CITER(0, NOWAIT, VMW(0));            // t = 22; completes tile 23
  CITER(1, NOWAIT, NOWAIT);            // t = 23
  asm volatile("s_waitcnt vmcnt(0) lgkmcnt(0)" ::: "memory");
  __syncthreads();
}

// ---------------------------------------------------------------------------
// Pass 1: k/v GEMM + fused p2-weighted reduction (in-register epilogue).
// Grid (6, 256) = 1536 blocks = 3 EXACT rounds at 2 blocks/CU.
// B-tile cols interleave k and v (r8-verified WQROW mapping); per block
// 128 rows x 256 kv-cols.  Epilogue identical math to r8, 4 ai instead of 8.
// ---------------------------------------------------------------------------
__global__ __launch_bounds__(512, 4) void kv_gemm_reduce(const bf16* __restrict__ A,
                                                         const bf16* __restrict__ B,
                                                         const float* __restrict__ p2,
                                                         float* __restrict__ partials) {
  __shared__ __align__(16) bf16 sh[24576];     // 48 KB staging
  __shared__ float red2[2][4][2][16];

  const int lin  = blockIdx.y * 6 + blockIdx.x;   // 0..1535
  const int xcd  = lin & 7;
  const int j    = lin >> 3;                 // 0..191
  const int hh   = j % 6;
  const int mblk = xcd + 8 * (j / 6);        // 0..255, bijective
  const int m0   = mblk * 128;
  const int h0   = hh * 2;

  const int tid = threadIdx.x;
  const int tr  = tid >> 2;                                // 0..127
  const int tc  = ((tid & 3) ^ ((tid >> 3) & 3)) * 8;      // pre-swizzled col
  const bf16* cA = A + (size_t)(m0 + tr) * 768 + tc;
#define WQROW(r) (768 + (((r) >> 4) & 1) * 768 + (h0 + ((r) >> 7)) * 64 + \
                  ((((r) >> 5) & 3) * 16 + ((r) & 15)))
  const bf16* cB0 = B + (size_t)WQROW(tr) * 768 + tc;
  const bf16* cB1 = B + (size_t)WQROW(128 + tr) * 768 + tc;
#undef WQROW

  f32x4 acc[4][4] = {};
  gemmC(cA, cB0, cB1, sh, acc);

  // in-register reduce (r8-verified): bj even = k, bj odd = v, same d
  const int lane = tid & 63, wave = tid >> 6;
  const int wm = wave >> 2, wn = wave & 3, l16 = lane & 15, qg = lane >> 4;
  const float* p2h = p2 + (size_t)(h0 + (wn >> 1)) * 4096 + (m0 & 4095) + wm * 64;
  float s0 = 0.f, s1 = 0.f;
#pragma unroll
  for (int ai = 0; ai < 4; ++ai) {
    const float4 w = *(const float4*)(p2h + ai * 16 + qg * 4);
    s0 += w.x * acc[ai][0][0] * acc[ai][1][0] + w.y * acc[ai][0][1] * acc[ai][1][1]
        + w.z * acc[ai][0][2] * acc[ai][1][2] + w.w * acc[ai][0][3] * acc[ai][1][3];
    s1 += w.x * acc[ai][2][0] * acc[ai][3][0] + w.y * acc[ai][2][1] * acc[ai][3][1]
        + w.z * acc[ai][2][2] * acc[ai][3][2] + w.w * acc[ai][2][3] * acc[ai][3][3];
  }
  s0 += __shfl_xor(s0, 16); s0 += __shfl_xor(s0, 32);
  s1 += __shfl_xor(s1, 16); s1 += __shfl_xor(s1, 32);
  if (qg == 0) { red2[wm][wn][0][l16] = s0; red2[wm][wn][1][l16] = s1; }
  __syncthreads();
  if (tid < 128) {
    const int l = tid & 15, jj = (tid >> 4) & 1, wnn = tid >> 5;
    const float v = red2[0][wnn][jj][l] + red2[1][wnn][jj][l];
    const int hx = h0 + (wnn >> 1);
    const int dd = ((wnn & 1) * 2 + jj) * 16 + l;
    partials[((size_t)mblk * 12 + hx) * 64 + dd] = v;
  }
}

// ---------------------------------------------------------------------------
// Pass 2: q GEMM + FUSED LayerNorm + modulation.  Grid (3, 256) = 768.
// Prologue: block LNs its own 4 heads from partials (32 mblk per batch);
// removes the mod_reduce_ln kernel + its launch gap.
// amod[m, c] = q[m, c] * p1[h(c), n(m)] * mod[b(m), c]  (bf16 out)
// ---------------------------------------------------------------------------
__global__ __launch_bounds__(512, 4) void q_gemm_mod(const bf16* __restrict__ A,
                                                     const bf16* __restrict__ B,
                                                     const float* __restrict__ p1,
                                                     const float* __restrict__ partials,
                                                     const float* __restrict__ gamma,
                                                     const float* __restrict__ beta,
                                                     bf16* __restrict__ amod) {
  __shared__ __align__(16) bf16 sh[24576];
  __shared__ float mod_s[4][64];

  const int lin  = blockIdx.y * 3 + blockIdx.x;   // 0..767
  const int xcd  = lin & 7;
  const int j    = lin >> 3;                 // 0..95
  const int nblk = j % 3;
  const int mblk = xcd + 8 * (j / 3);        // 0..255
  const int n0   = nblk * 256;
  const int m0   = mblk * 128;
  const int b    = mblk >> 5;
  const int h0q  = nblk * 4;

  const int tid = threadIdx.x;
  // ---- fused LN: waves 0-3 each handle one head (64 lanes = 64 d)
  if (tid < 256) {
    const int hl = tid >> 6, d = tid & 63;
    const float* p = partials + ((size_t)(b * 32) * 12 + h0q + hl) * 64 + d;
    float s = 0.f;
#pragma unroll
    for (int mb = 0; mb < 32; ++mb) s += p[(size_t)mb * 12 * 64];
    float sum = s, sumsq = s * s;
#pragma unroll
    for (int o = 32; o > 0; o >>= 1) {
      sum += __shfl_xor(sum, o); sumsq += __shfl_xor(sumsq, o);
    }
    const float mu  = sum * (1.f / 64.f);
    const float var = sumsq * (1.f / 64.f) - mu * mu;
    mod_s[hl][d] = (s - mu) * rsqrtf(var + LN_EPS) * gamma[d] + beta[d];
  }
  __syncthreads();

  const int tr = tid >> 2;
  const int tc = ((tid & 3) ^ ((tid >> 3) & 3)) * 8;
  const bf16* cA  = A + (size_t)(m0 + tr) * 768 + tc;
  const bf16* cB0 = B + (size_t)(n0 + tr) * 768 + tc;
  const bf16* cB1 = B + (size_t)(n0 + 128 + tr) * 768 + tc;

  f32x4 acc[4][4] = {};
  gemmC(cA, cB0, cB1, sh, acc);

  const int lane = tid & 63, wave = tid >> 6;
  const int wm = wave >> 2, wn = wave & 3, l16 = lane & 15, qg = lane >> 4;
  const int row0 = m0 + wm * 64 + qg * 4;
  const int col0 = n0 + wn * 64 + l16;
  const int h    = h0q + wn;                   // wave-uniform head

  float p1v[4][4];
#pragma unroll
  for (int ai = 0; ai < 4; ++ai)
#pragma unroll
    for (int r = 0; r < 4; ++r)
      p1v[ai][r] = p1[(size_t)h * 4096 + ((row0 + ai * 16 + r) & 4095)];
  float mv[4];
#pragma unroll
  for (int bj = 0; bj < 4; ++bj) mv[bj] = mod_s[wn][bj * 16 + l16];

#pragma unroll
  for (int ai = 0; ai < 4; ++ai)
#pragma unroll
    for (int bj = 0; bj < 4; ++bj)
#pragma unroll
      for (int r = 0; r < 4; ++r)
        amod[(size_t)(row0 + ai * 16 + r) * 768 + col0 + bj * 16] =
            (bf16)(acc[ai][bj][r] * p1v[ai][r] * mv[bj]);
}

// ---------------------------------------------------------------------------
// Pass 3: out fp32 = amod @ w_proj^T + b_proj.  Grid (3, 256) = 768 blocks.
// ---------------------------------------------------------------------------
__global__ __launch_bounds__(512, 4) void gemm_proj(const bf16* __restrict__ A,
                                                    const bf16* __restrict__ B,
                                                    const float* __restrict__ bias,
                                                    float* __restrict__ C) {
  __shared__ __align__(16) bf16 sh[24576];

  const int lin  = blockIdx.y * 3 + blockIdx.x;
  const int xcd  = lin & 7;
  const int j    = lin >> 3;
  const int nblk = j % 3;
  const int mblk = xcd + 8 * (j / 3);
  const int n0   = nblk * 256;
  const int m0   = mblk * 128;

  const int tid = threadIdx.x;
  const int tr  = tid >> 2;
  const int tc  = ((tid & 3) ^ ((tid >> 3) & 3)) * 8;
  const bf16* cA  = A + (size_t)(m0 + tr) * 768 + tc;
  const bf16* cB0 = B + (size_t)(n0 + tr) * 768 + tc;
  const bf16* cB1 = B + (size_t)(n0 + 128 + tr) * 768 + tc;

  f32x4 acc[4][4] = {};
  gemmC(cA, cB0, cB1, sh, acc);

  const int lane = tid & 63, wave = tid >> 6;
  const int wm = wave >> 2, wn = wave & 3, l16 = lane & 15, qg = lane >> 4;
  const int row0 = m0 + wm * 64 + qg * 4;
  const int col0 = n0 + wn * 64 + l16;
#pragma unroll
  for (int bj = 0; bj < 4; ++bj) {
    const int col = col0 + bj * 16;
    const float bv = bias[col];
#pragma unroll
    for (int ai = 0; ai < 4; ++ai)
#pragma unroll
      for (int r = 0; r < 4; ++r)
        C[(size_t)(row0 + ai * 16 + r) * 768 + col] = acc[ai][bj][r] + bv;
  }
}

// ---------------------------------------------------------------------------
extern "C" void kernel_launch(void* const* d_in, const int* in_sizes, int n_in,
                              void* d_out, int out_size, void* d_ws, size_t ws_size,
                              hipStream_t stream) {
  (void)in_sizes; (void)n_in; (void)out_size; (void)ws_size;

  const float* x      = (const float*)d_in[0];   // [8,4096,768]
  const float* w_qkv  = (const float*)d_in[1];   // [2304,768]
  const float* w_proj = (const float*)d_in[2];   // [768,768]
  const float* b_proj = (const float*)d_in[3];   // [768]
  const float* p1     = (const float*)d_in[4];   // [12,4096]
  const float* p2     = (const float*)d_in[5];   // [12,4096]
  const float* gamma  = (const float*)d_in[6];   // [64]
  const float* beta   = (const float*)d_in[7];   // [64]
  float* out = (float*)d_out;                    // [8,4096,768] fp32

  char* ws = (char*)d_ws;
  bf16*  xb       = (bf16*)(ws + 0);              // 50,331,648  x bf16 [32768,768]
  bf16*  wqb      = (bf16*)(ws + 50331648);       //  3,538,944  w_qkv bf16
  bf16*  wpb      = (bf16*)(ws + 53870592);       //  1,179,648  w_proj bf16
  bf16*  amod     = (bf16*)(ws + 55050240);       // 50,331,648  amod bf16 [32768,768]
  float* partials = (float*)(ws + 105381888);     //    786,432  [256][12][64] f32

  // 1) fp32 -> bf16 conversions, grid-strided (1680 blocks x 16 iters exact)
  cvt_all<<<1680, 256, 0, stream>>>(x, w_qkv, w_proj, xb, wqb, wpb);

  // 2) k/v GEMM + fused p2*k*v reduction (3 exact rounds @ 2 blocks/CU)
  kv_gemm_reduce<<<dim3(6, 256), 512, 0, stream>>>(xb, wqb, p2, partials);

  // 3) q GEMM + fused LayerNorm + p1/mod modulation -> amod bf16
  q_gemm_mod<<<dim3(3, 256), 512, 0, stream>>>(xb, wqb, p1, partials,
                                               gamma, beta, amod);

  // 4) proj GEMM + bias -> out fp32
  gemm_proj<<<dim3(3, 256), 512, 0, stream>>>(amod, wpb, b_proj, out);
}